// Round 1
// 2961.981 us; speedup vs baseline: 1.7720x; 1.7720x over previous
//
#include <hip/hip_runtime.h>

// PA_MSA: MFMA bf16 GEMM replaces VALU GEMM probe.
// B=4, C=384, H=W=128, heads=8, ch=48.
// mgemm_k: 128x128 tile, BK=64, 4 waves x (64x64), mfma_f32_16x16x32_bf16,
// reg-staged LDS with XOR-16B-chunk swizzle (write & read both swizzled).

typedef unsigned short u16;
typedef __attribute__((ext_vector_type(8))) short s16x8;
typedef __attribute__((ext_vector_type(4))) short s16x4;
typedef __attribute__((ext_vector_type(4))) float f32x4;
typedef __attribute__((ext_vector_type(8))) __bf16 bf16x8;

#define P_HW 16384
#define C_DIM 384

__device__ __forceinline__ u16 f2b(float f) {
  union { float f; unsigned u; } v; v.f = f;
  unsigned u = v.u;
  return (u16)((u + 0x7FFFu + ((u >> 16) & 1u)) >> 16);  // RNE
}
__device__ __forceinline__ float b2f(u16 h) {
  union { unsigned u; float f; } v; v.u = ((unsigned)h) << 16; return v.f;
}

// ---------- utility ----------
__global__ void zerof_k(float* __restrict__ p, int n) {
  int i = blockIdx.x * 256 + threadIdx.x;
  if (i < n) p[i] = 0.f;
}

// fp32 NCHW (384,16384) -> bf16 NHWC (16384,384), one batch
__global__ __launch_bounds__(256) void tcvt_k(const float* __restrict__ in, u16* __restrict__ out) {
  const int tid = threadIdx.x;
  const int c0 = blockIdx.x * 32 + (tid & 3) * 8;
  const int p  = blockIdx.y * 64 + (tid >> 2);
  u16 tmp[8];
#pragma unroll
  for (int u = 0; u < 8; u++) tmp[u] = f2b(in[(size_t)(c0 + u) * P_HW + p]);
  *(s16x8*)(out + (size_t)p * C_DIM + c0) = *(s16x8*)tmp;
}

// convert the 5 weight matrices fp32 -> bf16, concatenated into dst.
// regions: [0,147456) w_q | [147456,294912) w_qT | [294912,589824) w_qcat
//          [589824,737280) w_k | [737280,884736) w_v
__global__ __launch_bounds__(256) void cvtw_k(const float* __restrict__ w_q, const float* __restrict__ w_qT,
                                              const float* __restrict__ w_qcat, const float* __restrict__ w_k,
                                              const float* __restrict__ w_v, u16* __restrict__ dst) {
  int i = blockIdx.x * 256 + threadIdx.x;
  if (i >= 884736) return;
  float v;
  if (i < 147456) v = w_q[i];
  else if (i < 294912) v = w_qT[i - 147456];
  else if (i < 589824) v = w_qcat[i - 294912];
  else if (i < 737280) v = w_k[i - 589824];
  else v = w_v[i - 737280];
  dst[i] = f2b(v);
}

// ---------- MFMA GEMM: out[o][p] = sum_c W[o][c] * Act[p][c] ----------
// Wb bf16 [384][K] row-major. Act NHWC bf16 [16384][384]; for K=768,
// chunk kc<384 reads B1, kc>=384 reads B2 (kk = kc-384).
// mode 0: NHWC bf16 out [p][o]; mode 2: NCHW bf16 out [o][p].
// Grid (128, 3), block 256 (4 waves, each 64x64 of the 128x128 tile).
__global__ __launch_bounds__(256) void mgemm_k(const u16* __restrict__ Wb,
    const u16* __restrict__ B1, const u16* __restrict__ B2,
    u16* __restrict__ outp, int K, int mode) {
  __shared__ __align__(16) u16 lA[128 * 64];  // weights tile [o_local][k], 16KB
  __shared__ __align__(16) u16 lB[128 * 64];  // act tile [p_local][k], 16KB
  const int tid = threadIdx.x;
  const int lane = tid & 63;
  const int wv = tid >> 6;
  const int wo = (wv >> 1) * 64;   // wave o-offset in tile
  const int wp = (wv & 1) * 64;    // wave p-offset in tile
  const int o0 = blockIdx.y * 128;
  const int p0 = blockIdx.x * 128;
  const int fr = lane & 15;        // A row (o) / B row (p) within 16x16 frag
  const int fg = lane >> 4;        // k-group (8 contiguous k each)
  const int sr = tid >> 3;         // staging row base (0..31)
  const int sc = tid & 7;          // staging 16B-chunk (0..7)

  f32x4 acc[4][4] = {};            // [mo][np]

  for (int kc = 0; kc < K; kc += 64) {
    const u16* Bsrc = (kc < 384) ? B1 : B2;
    const int kk = (kc < 384) ? kc : kc - 384;
    __syncthreads();
#pragma unroll
    for (int s = 0; s < 4; s++) {
      const int r = sr + s * 32;
      const int slot = (sc ^ (r & 7)) * 8;   // XOR swizzle, 16B granularity
      *(s16x8*)&lA[r * 64 + slot] = *(const s16x8*)(Wb + (size_t)(o0 + r) * K + kc + sc * 8);
      *(s16x8*)&lB[r * 64 + slot] = *(const s16x8*)(Bsrc + (size_t)(p0 + r) * C_DIM + kk + sc * 8);
    }
    __syncthreads();
#pragma unroll
    for (int ks = 0; ks < 2; ks++) {   // two k=32 sub-steps of BK=64
      bf16x8 af[4], bfv[4];
#pragma unroll
      for (int i = 0; i < 4; i++) {
        const int ra = wo + i * 16 + fr;
        af[i]  = *(const bf16x8*)&lA[ra * 64 + (((ks * 4 + fg) ^ (ra & 7)) * 8)];
        const int rb = wp + i * 16 + fr;
        bfv[i] = *(const bf16x8*)&lB[rb * 64 + (((ks * 4 + fg) ^ (rb & 7)) * 8)];
      }
#pragma unroll
      for (int mo = 0; mo < 4; mo++)
#pragma unroll
        for (int np = 0; np < 4; np++)
          acc[mo][np] = __builtin_amdgcn_mfma_f32_16x16x32_bf16(af[mo], bfv[np], acc[mo][np], 0, 0, 0);
    }
  }

  // D layout: row(o) = fg*4 + reg, col(p) = fr  (within each 16x16 frag)
  const int dg = fg * 4;
  if (mode == 0) {
#pragma unroll
    for (int np = 0; np < 4; np++) {
      const int p = p0 + wp + np * 16 + fr;
      u16* dst = outp + (size_t)p * C_DIM + o0 + wo + dg;
#pragma unroll
      for (int mo = 0; mo < 4; mo++) {
        u16 t4[4];
#pragma unroll
        for (int r = 0; r < 4; r++) t4[r] = f2b(acc[mo][np][r]);
        *(s16x4*)(dst + mo * 16) = *(const s16x4*)t4;
      }
    }
  } else {
#pragma unroll
    for (int mo = 0; mo < 4; mo++)
#pragma unroll
      for (int r = 0; r < 4; r++) {
        const int o = o0 + wo + mo * 16 + dg + r;
        u16* dst = outp + (size_t)o * P_HW + p0 + wp + fr;
#pragma unroll
        for (int np = 0; np < 4; np++) dst[np * 16] = f2b(acc[mo][np][r]);
      }
  }
}

// ---------- depthwise 3x3, NHWC bf16 -> NHWC bf16 (one batch) ----------
__global__ __launch_bounds__(384) void dw_nhwc_k(const u16* __restrict__ in, u16* __restrict__ out,
                                                 const float* __restrict__ w) {
  const int c = threadIdx.x;
  const int y = blockIdx.x;
  float wr[9];
#pragma unroll
  for (int t = 0; t < 9; t++) wr[t] = w[c * 9 + t];
  const u16* base = in + c;
  u16* obase = out + c;
  auto ld = [&](int yy, int xx) -> float {
    if (yy < 0 || yy > 127 || xx < 0 || xx > 127) return 0.f;
    return b2f(base[((size_t)(yy * 128 + xx)) * C_DIM]);
  };
  float a0 = ld(y - 1, 0), a1 = ld(y, 0), a2 = ld(y + 1, 0);
  float p0 = 0.f, p1 = 0.f, p2 = 0.f;
  for (int x = 0; x < 128; x++) {
    float c0 = ld(y - 1, x + 1), c1 = ld(y, x + 1), c2 = ld(y + 1, x + 1);
    float acc = p0 * wr[0] + a0 * wr[1] + c0 * wr[2]
              + p1 * wr[3] + a1 * wr[4] + c1 * wr[5]
              + p2 * wr[6] + a2 * wr[7] + c2 * wr[8];
    obase[((size_t)(y * 128 + x)) * C_DIM] = f2b(acc);
    p0 = a0; p1 = a1; p2 = a2; a0 = c0; a1 = c1; a2 = c2;
  }
}

// ---------- depthwise 3x3, NCHW bf16 -> NCHW bf16 (one batch) ----------
__global__ __launch_bounds__(256) void dw_nchw_k(const u16* __restrict__ in, u16* __restrict__ out,
                                                 const float* __restrict__ w) {
  const int tid = threadIdx.x;
  const int x = tid & 127;
  const int y = blockIdx.x * 2 + (tid >> 7);
  const int c = blockIdx.y;
  float wr[9];
#pragma unroll
  for (int t = 0; t < 9; t++) wr[t] = w[c * 9 + t];
  const u16* base = in + (size_t)c * P_HW;
  float acc = 0.f;
#pragma unroll
  for (int ky = 0; ky < 3; ky++) {
    int yy = y + ky - 1;
    if (yy < 0 || yy > 127) continue;
#pragma unroll
    for (int kx = 0; kx < 3; kx++) {
      int xx = x + kx - 1;
      if (xx < 0 || xx > 127) continue;
      acc += b2f(base[yy * 128 + xx]) * wr[ky * 3 + kx];
    }
  }
  out[(size_t)c * P_HW + y * 128 + x] = f2b(acc);
}

// ---------- per-row sum of squares (one batch; z: 0=q,1=k) ----------
__global__ __launch_bounds__(256) void row_sumsq_k(const u16* __restrict__ q, const u16* __restrict__ k,
                                                   float* __restrict__ nq, float* __restrict__ nk) {
  const int c = blockIdx.x, t = blockIdx.z;
  const u16* src = (t == 0) ? q : k;
  float* dst = (t == 0) ? nq : nk;
  const u16* row = src + (size_t)c * P_HW;
  float s = 0.f;
  for (int i = threadIdx.x * 8; i < P_HW; i += 2048) {
    s16x8 v = *(const s16x8*)(row + i);
#pragma unroll
    for (int j = 0; j < 8; j++) { float f = b2f((u16)v[j]); s += f * f; }
  }
  __shared__ float red[256];
  red[threadIdx.x] = s;
  __syncthreads();
  for (int off = 128; off > 0; off >>= 1) {
    if (threadIdx.x < off) red[threadIdx.x] += red[threadIdx.x + off];
    __syncthreads();
  }
  if (threadIdx.x == 0) dst[c] = red[0];
}

// ---------- naive Gram (one batch): G[h][i][j] += sum_p q[i,p] k[j,p] ----------
__global__ __launch_bounds__(256) void gramn_k(const u16* __restrict__ q, const u16* __restrict__ k,
                                               float* __restrict__ G) {
  const int pair = blockIdx.x * 256 + threadIdx.x;  // [0, 2304)
  const int h = blockIdx.y;
  const int chunk = blockIdx.z;
  const int i = pair / 48, j = pair % 48;
  const u16* qrow = q + (size_t)(h * 48 + i) * P_HW;
  const u16* krow = k + (size_t)(h * 48 + j) * P_HW;
  const int p0 = chunk * 2048;
  float acc = 0.f;
  for (int p = p0; p < p0 + 2048; p += 8) {
    s16x8 qa = *(const s16x8*)(qrow + p);
    s16x8 ka = *(const s16x8*)(krow + p);
#pragma unroll
    for (int u = 0; u < 8; u++) acc += b2f((u16)qa[u]) * b2f((u16)ka[u]);
  }
  atomicAdd(&G[((size_t)h * 48 + i) * 48 + j], acc);
}

// ---------- softmax (one batch): fp32 attn out [8][48][48] ----------
__global__ void attn_softmax_k(const float* __restrict__ G, const float* __restrict__ nqA,
                               const float* __restrict__ nkA, const float* __restrict__ temp,
                               float* __restrict__ attnf) {
  const int h = blockIdx.x;
  const int i = threadIdx.x;
  __shared__ float mk[48];
  if (i < 48) mk[i] = fmaxf(sqrtf(nkA[h * 48 + i]), 1e-12f);
  __syncthreads();
  if (i < 48) {
    float mq = fmaxf(sqrtf(nqA[h * 48 + i]), 1e-12f);
    float T = temp[h];
    const float* g = G + ((size_t)h * 48 + i) * 48;
    float L[48];
    float mx = -1e30f;
    for (int j = 0; j < 48; j++) {
      L[j] = T * g[j] / (mq * mk[j]);
      mx = fmaxf(mx, L[j]);
    }
    float sum = 0.f;
    for (int j = 0; j < 48; j++) { L[j] = expf(L[j] - mx); sum += L[j]; }
    float inv = 1.f / sum;
    float* d = attnf + ((size_t)h * 48 + i) * 48;
    for (int j = 0; j < 48; j++) d[j] = L[j] * inv;
  }
}

// ---------- naive AV (one batch): out[h*48+i][p] = sum_j attn[h][i][j] v[p][h*48+j] ----------
__global__ __launch_bounds__(256) void avn_k(const float* __restrict__ attnf, const u16* __restrict__ v,
                                             float* __restrict__ out) {
  __shared__ float la[2304];
  const int tid = threadIdx.x;
  const int p = blockIdx.x * 256 + tid;
  const u16* vp = v + (size_t)p * C_DIM;
  for (int h = 0; h < 8; h++) {
    __syncthreads();
    for (int idx = tid; idx < 2304; idx += 256) la[idx] = attnf[h * 2304 + idx];
    __syncthreads();
    float vf[48];
#pragma unroll
    for (int s = 0; s < 6; s++) {
      s16x8 t8 = *(const s16x8*)(vp + h * 48 + s * 8);
#pragma unroll
      for (int u = 0; u < 8; u++) vf[s * 8 + u] = b2f((u16)t8[u]);
    }
    for (int i = 0; i < 48; i++) {
      const float* row = &la[i * 48];
      float acc = 0.f;
#pragma unroll
      for (int j = 0; j < 48; j += 4) {
        acc += row[j] * vf[j] + row[j + 1] * vf[j + 1] + row[j + 2] * vf[j + 2] + row[j + 3] * vf[j + 3];
      }
      out[(size_t)(h * 48 + i) * P_HW + p] = acc;
    }
  }
}

// ---------- launch ----------
extern "C" void kernel_launch(void* const* d_in, const int* in_sizes, int n_in,
                              void* d_out, int out_size, void* d_ws, size_t ws_size,
                              hipStream_t stream) {
  const float* x      = (const float*)d_in[0];
  const float* t      = (const float*)d_in[1];
  const float* w_q    = (const float*)d_in[2];
  const float* w_q_dw = (const float*)d_in[3];
  const float* w_qT   = (const float*)d_in[4];
  const float* w_qT_dw= (const float*)d_in[5];
  const float* w_qcat = (const float*)d_in[6];
  const float* w_k    = (const float*)d_in[7];
  const float* w_k_dw = (const float*)d_in[8];
  const float* w_v    = (const float*)d_in[9];
  const float* w_v_dw = (const float*)d_in[10];
  const float* temp   = (const float*)d_in[11];
  float* out = (float*)d_out;

  // ws: G[32*2304] nq[1536] nk[1536] attnf[32*2304] then 4 bf16 buffers (12.58MB each)
  float* G     = (float*)d_ws;
  float* nq    = G + 73728;
  float* nk    = nq + 1536;
  float* attnf = nk + 1536;
  u16* bufs = (u16*)(attnf + 73728);        // byte offset 602112, 16B-aligned
  const size_t BUFE = (size_t)P_HW * C_DIM; // 6,291,456 elems
  u16* A = bufs;
  u16* Bb = A + BUFE;
  u16* Cb = Bb + BUFE;
  u16* Db = Cb + BUFE;

  // bf16 weights live in the second half of batch-3's output quarter:
  // that region is untouched until batch-3's final avn_k (which runs after
  // the last GEMM use of the weights).
  u16* Wscr = (u16*)(out + (size_t)3 * C_DIM * P_HW) + BUFE;
  u16* WQ    = Wscr;
  u16* WQT   = Wscr + 147456;
  u16* WQCAT = Wscr + 294912;
  u16* WK    = Wscr + 589824;
  u16* WV    = Wscr + 737280;

  zerof_k<<<288, 256, 0, stream>>>(G, 73728);
  cvtw_k<<<3456, 256, 0, stream>>>(w_q, w_qT, w_qcat, w_k, w_v, Wscr);

  for (int b = 0; b < 4; b++) {
    const float* xb = x + (size_t)b * C_DIM * P_HW;
    const float* tb = t + (size_t)b * C_DIM * P_HW;
    float* outb = out + (size_t)b * C_DIM * P_HW;
    u16* O = (u16*)outb;                    // batch-local scratch inside own out region
    float* Gb = G + (size_t)b * 8 * 2304;
    float* nqb = nq + (size_t)b * C_DIM;
    float* nkb = nk + (size_t)b * C_DIM;
    float* attnb = attnf + (size_t)b * 8 * 2304;

    tcvt_k<<<dim3(12, 256), 256, 0, stream>>>(tb, A);                       // t -> A (NHWC)
    mgemm_k<<<dim3(128, 3), 256, 0, stream>>>(WQT, A, A, Bb, 384, 0);       // qT -> B
    dw_nhwc_k<<<128, 384, 0, stream>>>(Bb, A, w_qT_dw);                     // qtd -> A
    tcvt_k<<<dim3(12, 256), 256, 0, stream>>>(xb, Bb);                      // x -> B
    mgemm_k<<<dim3(128, 3), 256, 0, stream>>>(WK, Bb, Bb, Cb, 384, 2);      // k (NCHW) -> C
    dw_nchw_k<<<dim3(64, 384), 256, 0, stream>>>(Cb, Db, w_k_dw);           // kd -> D
    mgemm_k<<<dim3(128, 3), 256, 0, stream>>>(WQ, Bb, Bb, Cb, 384, 0);      // q -> C
    dw_nhwc_k<<<128, 384, 0, stream>>>(Cb, O, w_q_dw);                      // qd -> O
    mgemm_k<<<dim3(128, 3), 256, 0, stream>>>(WV, Bb, Bb, Cb, 384, 0);      // v -> C
    dw_nhwc_k<<<128, 384, 0, stream>>>(Cb, Bb, w_v_dw);                     // vd -> B
    mgemm_k<<<dim3(128, 3), 256, 0, stream>>>(WQCAT, O, A, Cb, 768, 2);     // qf (NCHW) -> C
    row_sumsq_k<<<dim3(384, 1, 2), 256, 0, stream>>>(Cb, Db, nqb, nkb);
    gramn_k<<<dim3(9, 8, 8), 256, 0, stream>>>(Cb, Db, Gb);
    attn_softmax_k<<<8, 64, 0, stream>>>(Gb, nqb, nkb, temp, attnb);
    avn_k<<<64, 256, 0, stream>>>(attnb, Bb, outb);
  }
}

// Round 2
// 1470.477 us; speedup vs baseline: 3.5694x; 2.0143x over previous
//
#include <hip/hip_runtime.h>

// PA_MSA: MFMA bf16 GEMM + parallel tap-major depthwise conv.
// B=4, C=384, H=W=128, heads=8, ch=48.

typedef unsigned short u16;
typedef __attribute__((ext_vector_type(8))) short s16x8;
typedef __attribute__((ext_vector_type(4))) short s16x4;
typedef __attribute__((ext_vector_type(4))) float f32x4;
typedef __attribute__((ext_vector_type(8))) __bf16 bf16x8;

#define P_HW 16384
#define C_DIM 384

__device__ __forceinline__ u16 f2b(float f) {
  union { float f; unsigned u; } v; v.f = f;
  unsigned u = v.u;
  return (u16)((u + 0x7FFFu + ((u >> 16) & 1u)) >> 16);  // RNE
}
__device__ __forceinline__ float b2f(u16 h) {
  union { unsigned u; float f; } v; v.u = ((unsigned)h) << 16; return v.f;
}

// ---------- utility ----------
__global__ void zerof_k(float* __restrict__ p, int n) {
  int i = blockIdx.x * 256 + threadIdx.x;
  if (i < n) p[i] = 0.f;
}

// fp32 NCHW (384,16384) -> bf16 NHWC (16384,384), one batch
__global__ __launch_bounds__(256) void tcvt_k(const float* __restrict__ in, u16* __restrict__ out) {
  const int tid = threadIdx.x;
  const int c0 = blockIdx.x * 32 + (tid & 3) * 8;
  const int p  = blockIdx.y * 64 + (tid >> 2);
  u16 tmp[8];
#pragma unroll
  for (int u = 0; u < 8; u++) tmp[u] = f2b(in[(size_t)(c0 + u) * P_HW + p]);
  *(s16x8*)(out + (size_t)p * C_DIM + c0) = *(s16x8*)tmp;
}

// convert the 5 weight matrices fp32 -> bf16, concatenated into dst.
__global__ __launch_bounds__(256) void cvtw_k(const float* __restrict__ w_q, const float* __restrict__ w_qT,
                                              const float* __restrict__ w_qcat, const float* __restrict__ w_k,
                                              const float* __restrict__ w_v, u16* __restrict__ dst) {
  int i = blockIdx.x * 256 + threadIdx.x;
  if (i >= 884736) return;
  float v;
  if (i < 147456) v = w_q[i];
  else if (i < 294912) v = w_qT[i - 147456];
  else if (i < 589824) v = w_qcat[i - 294912];
  else if (i < 737280) v = w_k[i - 589824];
  else v = w_v[i - 737280];
  dst[i] = f2b(v);
}

// transpose dw weights (C,1,3,3) -> [tap][c] float, 3 matrices (q, qT, v)
__global__ __launch_bounds__(384) void cvtdw_k(const float* __restrict__ w_q_dw,
                                               const float* __restrict__ w_qT_dw,
                                               const float* __restrict__ w_v_dw,
                                               float* __restrict__ dst) {
  const int c = threadIdx.x;
  const float* src = (blockIdx.x == 0) ? w_q_dw : (blockIdx.x == 1) ? w_qT_dw : w_v_dw;
  float* d = dst + blockIdx.x * 3456;
#pragma unroll
  for (int t = 0; t < 9; t++) d[t * C_DIM + c] = src[c * 9 + t];
}

// ---------- MFMA GEMM: out[o][p] = sum_c W[o][c] * Act[p][c] ----------
// Grid (128, 3), block 256 (4 waves, each 64x64 of the 128x128 tile).
__global__ __launch_bounds__(256) void mgemm_k(const u16* __restrict__ Wb,
    const u16* __restrict__ B1, const u16* __restrict__ B2,
    u16* __restrict__ outp, int K, int mode) {
  __shared__ __align__(16) u16 lA[128 * 64];  // weights tile [o_local][k], 16KB
  __shared__ __align__(16) u16 lB[128 * 64];  // act tile [p_local][k], 16KB
  const int tid = threadIdx.x;
  const int lane = tid & 63;
  const int wv = tid >> 6;
  const int wo = (wv >> 1) * 64;   // wave o-offset in tile
  const int wp = (wv & 1) * 64;    // wave p-offset in tile
  const int o0 = blockIdx.y * 128;
  const int p0 = blockIdx.x * 128;
  const int fr = lane & 15;        // A row (o) / B row (p) within 16x16 frag
  const int fg = lane >> 4;        // k-group (8 contiguous k each)
  const int sr = tid >> 3;         // staging row base (0..31)
  const int sc = tid & 7;          // staging 16B-chunk (0..7)

  f32x4 acc[4][4] = {};            // [mo][np]

  for (int kc = 0; kc < K; kc += 64) {
    const u16* Bsrc = (kc < 384) ? B1 : B2;
    const int kk = (kc < 384) ? kc : kc - 384;
    __syncthreads();
#pragma unroll
    for (int s = 0; s < 4; s++) {
      const int r = sr + s * 32;
      const int slot = (sc ^ (r & 7)) * 8;   // XOR swizzle, 16B granularity
      *(s16x8*)&lA[r * 64 + slot] = *(const s16x8*)(Wb + (size_t)(o0 + r) * K + kc + sc * 8);
      *(s16x8*)&lB[r * 64 + slot] = *(const s16x8*)(Bsrc + (size_t)(p0 + r) * C_DIM + kk + sc * 8);
    }
    __syncthreads();
#pragma unroll
    for (int ks = 0; ks < 2; ks++) {   // two k=32 sub-steps of BK=64
      bf16x8 af[4], bfv[4];
#pragma unroll
      for (int i = 0; i < 4; i++) {
        const int ra = wo + i * 16 + fr;
        af[i]  = *(const bf16x8*)&lA[ra * 64 + (((ks * 4 + fg) ^ (ra & 7)) * 8)];
        const int rb = wp + i * 16 + fr;
        bfv[i] = *(const bf16x8*)&lB[rb * 64 + (((ks * 4 + fg) ^ (rb & 7)) * 8)];
      }
#pragma unroll
      for (int mo = 0; mo < 4; mo++)
#pragma unroll
        for (int np = 0; np < 4; np++)
          acc[mo][np] = __builtin_amdgcn_mfma_f32_16x16x32_bf16(af[mo], bfv[np], acc[mo][np], 0, 0, 0);
    }
  }

  // D layout: row(o) = fg*4 + reg, col(p) = fr  (within each 16x16 frag)
  const int dg = fg * 4;
  if (mode == 0) {
#pragma unroll
    for (int np = 0; np < 4; np++) {
      const int p = p0 + wp + np * 16 + fr;
      u16* dst = outp + (size_t)p * C_DIM + o0 + wo + dg;
#pragma unroll
      for (int mo = 0; mo < 4; mo++) {
        u16 t4[4];
#pragma unroll
        for (int r = 0; r < 4; r++) t4[r] = f2b(acc[mo][np][r]);
        *(s16x4*)(dst + mo * 16) = *(const s16x4*)t4;
      }
    }
  } else {
#pragma unroll
    for (int mo = 0; mo < 4; mo++)
#pragma unroll
      for (int r = 0; r < 4; r++) {
        const int o = o0 + wo + mo * 16 + dg + r;
        u16* dst = outp + (size_t)o * P_HW + p0 + wp + fr;
#pragma unroll
        for (int np = 0; np < 4; np++) dst[np * 16] = f2b(acc[mo][np][r]);
      }
  }
}

// ---------- depthwise 3x3, NHWC bf16 -> NHWC bf16, tap-major parallel ----------
// wT layout [9][384] float. Grid 2048, block 384: thread = (pixel_local 0..7, cgroup 0..47).
__global__ __launch_bounds__(384) void dw_nhwc_k(const u16* __restrict__ in, u16* __restrict__ out,
                                                 const float* __restrict__ wT) {
  const int tid = threadIdx.x;
  const int cg = tid % 48;
  const int pl = tid / 48;
  const int p = blockIdx.x * 8 + pl;
  const int y = p >> 7, x = p & 127;
  const int c0 = cg * 8;
  float acc[8] = {};
#pragma unroll
  for (int ky = 0; ky < 3; ky++) {
    const int yy = y + ky - 1;
    if (yy < 0 || yy > 127) continue;
#pragma unroll
    for (int kx = 0; kx < 3; kx++) {
      const int xx = x + kx - 1;
      if (xx < 0 || xx > 127) continue;
      s16x8 v8 = *(const s16x8*)(in + (size_t)(yy * 128 + xx) * C_DIM + c0);
      const float* wr = wT + (ky * 3 + kx) * C_DIM + c0;
      f32x4 w0 = *(const f32x4*)wr;
      f32x4 w1 = *(const f32x4*)(wr + 4);
#pragma unroll
      for (int u = 0; u < 4; u++) acc[u] += b2f((u16)v8[u]) * w0[u];
#pragma unroll
      for (int u = 0; u < 4; u++) acc[4 + u] += b2f((u16)v8[4 + u]) * w1[u];
    }
  }
  u16 tmp[8];
#pragma unroll
  for (int u = 0; u < 8; u++) tmp[u] = f2b(acc[u]);
  *(s16x8*)(out + (size_t)p * C_DIM + c0) = *(s16x8*)tmp;
}

// ---------- depthwise 3x3, NCHW bf16 -> NCHW bf16 (one batch) ----------
__global__ __launch_bounds__(256) void dw_nchw_k(const u16* __restrict__ in, u16* __restrict__ out,
                                                 const float* __restrict__ w) {
  const int tid = threadIdx.x;
  const int x = tid & 127;
  const int y = blockIdx.x * 2 + (tid >> 7);
  const int c = blockIdx.y;
  float wr[9];
#pragma unroll
  for (int t = 0; t < 9; t++) wr[t] = w[c * 9 + t];
  const u16* base = in + (size_t)c * P_HW;
  float acc = 0.f;
#pragma unroll
  for (int ky = 0; ky < 3; ky++) {
    int yy = y + ky - 1;
    if (yy < 0 || yy > 127) continue;
#pragma unroll
    for (int kx = 0; kx < 3; kx++) {
      int xx = x + kx - 1;
      if (xx < 0 || xx > 127) continue;
      acc += b2f(base[yy * 128 + xx]) * wr[ky * 3 + kx];
    }
  }
  out[(size_t)c * P_HW + y * 128 + x] = f2b(acc);
}

// ---------- per-row sum of squares (one batch; z: 0=q,1=k) ----------
__global__ __launch_bounds__(256) void row_sumsq_k(const u16* __restrict__ q, const u16* __restrict__ k,
                                                   float* __restrict__ nq, float* __restrict__ nk) {
  const int c = blockIdx.x, t = blockIdx.z;
  const u16* src = (t == 0) ? q : k;
  float* dst = (t == 0) ? nq : nk;
  const u16* row = src + (size_t)c * P_HW;
  float s = 0.f;
  for (int i = threadIdx.x * 8; i < P_HW; i += 2048) {
    s16x8 v = *(const s16x8*)(row + i);
#pragma unroll
    for (int j = 0; j < 8; j++) { float f = b2f((u16)v[j]); s += f * f; }
  }
  __shared__ float red[256];
  red[threadIdx.x] = s;
  __syncthreads();
  for (int off = 128; off > 0; off >>= 1) {
    if (threadIdx.x < off) red[threadIdx.x] += red[threadIdx.x + off];
    __syncthreads();
  }
  if (threadIdx.x == 0) dst[c] = red[0];
}

// ---------- naive Gram (one batch): G[h][i][j] += sum_p q[i,p] k[j,p] ----------
__global__ __launch_bounds__(256) void gramn_k(const u16* __restrict__ q, const u16* __restrict__ k,
                                               float* __restrict__ G) {
  const int pair = blockIdx.x * 256 + threadIdx.x;  // [0, 2304)
  const int h = blockIdx.y;
  const int chunk = blockIdx.z;
  const int i = pair / 48, j = pair % 48;
  const u16* qrow = q + (size_t)(h * 48 + i) * P_HW;
  const u16* krow = k + (size_t)(h * 48 + j) * P_HW;
  const int p0 = chunk * 2048;
  float acc = 0.f;
  for (int p = p0; p < p0 + 2048; p += 8) {
    s16x8 qa = *(const s16x8*)(qrow + p);
    s16x8 ka = *(const s16x8*)(krow + p);
#pragma unroll
    for (int u = 0; u < 8; u++) acc += b2f((u16)qa[u]) * b2f((u16)ka[u]);
  }
  atomicAdd(&G[((size_t)h * 48 + i) * 48 + j], acc);
}

// ---------- softmax (one batch): fp32 attn out [8][48][48] ----------
__global__ void attn_softmax_k(const float* __restrict__ G, const float* __restrict__ nqA,
                               const float* __restrict__ nkA, const float* __restrict__ temp,
                               float* __restrict__ attnf) {
  const int h = blockIdx.x;
  const int i = threadIdx.x;
  __shared__ float mk[48];
  if (i < 48) mk[i] = fmaxf(sqrtf(nkA[h * 48 + i]), 1e-12f);
  __syncthreads();
  if (i < 48) {
    float mq = fmaxf(sqrtf(nqA[h * 48 + i]), 1e-12f);
    float T = temp[h];
    const float* g = G + ((size_t)h * 48 + i) * 48;
    float L[48];
    float mx = -1e30f;
    for (int j = 0; j < 48; j++) {
      L[j] = T * g[j] / (mq * mk[j]);
      mx = fmaxf(mx, L[j]);
    }
    float sum = 0.f;
    for (int j = 0; j < 48; j++) { L[j] = expf(L[j] - mx); sum += L[j]; }
    float inv = 1.f / sum;
    float* d = attnf + ((size_t)h * 48 + i) * 48;
    for (int j = 0; j < 48; j++) d[j] = L[j] * inv;
  }
}

// ---------- AV (one batch): out[h*48+i][p] = sum_j attn[h][i][j] v[p][h*48+j] ----------
// grid (64, 8): by = head. Per-head LDS attn staging.
__global__ __launch_bounds__(256) void avn_k(const float* __restrict__ attnf, const u16* __restrict__ v,
                                             float* __restrict__ out) {
  __shared__ float la[2304];
  const int tid = threadIdx.x;
  const int h = blockIdx.y;
  const int p = blockIdx.x * 256 + tid;
  for (int idx = tid; idx < 2304; idx += 256) la[idx] = attnf[h * 2304 + idx];
  __syncthreads();
  const u16* vp = v + (size_t)p * C_DIM + h * 48;
  float vf[48];
#pragma unroll
  for (int s = 0; s < 6; s++) {
    s16x8 t8 = *(const s16x8*)(vp + s * 8);
#pragma unroll
    for (int u = 0; u < 8; u++) vf[s * 8 + u] = b2f((u16)t8[u]);
  }
  for (int i = 0; i < 48; i++) {
    const float* row = &la[i * 48];
    float acc = 0.f;
#pragma unroll
    for (int j = 0; j < 48; j += 4) {
      acc += row[j] * vf[j] + row[j + 1] * vf[j + 1] + row[j + 2] * vf[j + 2] + row[j + 3] * vf[j + 3];
    }
    out[(size_t)(h * 48 + i) * P_HW + p] = acc;
  }
}

// ---------- launch ----------
extern "C" void kernel_launch(void* const* d_in, const int* in_sizes, int n_in,
                              void* d_out, int out_size, void* d_ws, size_t ws_size,
                              hipStream_t stream) {
  const float* x      = (const float*)d_in[0];
  const float* t      = (const float*)d_in[1];
  const float* w_q    = (const float*)d_in[2];
  const float* w_q_dw = (const float*)d_in[3];
  const float* w_qT   = (const float*)d_in[4];
  const float* w_qT_dw= (const float*)d_in[5];
  const float* w_qcat = (const float*)d_in[6];
  const float* w_k    = (const float*)d_in[7];
  const float* w_k_dw = (const float*)d_in[8];
  const float* w_v    = (const float*)d_in[9];
  const float* w_v_dw = (const float*)d_in[10];
  const float* temp   = (const float*)d_in[11];
  float* out = (float*)d_out;

  // ws: G[32*2304] nq[1536] nk[1536] attnf[32*2304] then 4 bf16 buffers (12.58MB each)
  float* G     = (float*)d_ws;
  float* nq    = G + 73728;
  float* nk    = nq + 1536;
  float* attnf = nk + 1536;
  u16* bufs = (u16*)(attnf + 73728);        // byte offset 602112, 16B-aligned
  const size_t BUFE = (size_t)P_HW * C_DIM; // 6,291,456 elems
  u16* A = bufs;
  u16* Bb = A + BUFE;
  u16* Cb = Bb + BUFE;
  u16* Db = Cb + BUFE;

  // bf16 weights + transposed dw weights live in the second half of batch-3's
  // output quarter: untouched until batch-3's final avn_k (runs after all uses).
  u16* Wscr = (u16*)(out + (size_t)3 * C_DIM * P_HW) + BUFE;
  u16* WQ    = Wscr;
  u16* WQT   = Wscr + 147456;
  u16* WQCAT = Wscr + 294912;
  u16* WK    = Wscr + 589824;
  u16* WV    = Wscr + 737280;
  float* DWT   = (float*)(Wscr + 884736);   // 3 x [9][384] float
  float* DWT_Q  = DWT;
  float* DWT_QT = DWT + 3456;
  float* DWT_V  = DWT + 6912;

  zerof_k<<<288, 256, 0, stream>>>(G, 73728);
  cvtw_k<<<3456, 256, 0, stream>>>(w_q, w_qT, w_qcat, w_k, w_v, Wscr);
  cvtdw_k<<<3, 384, 0, stream>>>(w_q_dw, w_qT_dw, w_v_dw, DWT);

  for (int b = 0; b < 4; b++) {
    const float* xb = x + (size_t)b * C_DIM * P_HW;
    const float* tb = t + (size_t)b * C_DIM * P_HW;
    float* outb = out + (size_t)b * C_DIM * P_HW;
    u16* O = (u16*)outb;                    // batch-local scratch inside own out region
    float* Gb = G + (size_t)b * 8 * 2304;
    float* nqb = nq + (size_t)b * C_DIM;
    float* nkb = nk + (size_t)b * C_DIM;
    float* attnb = attnf + (size_t)b * 8 * 2304;

    tcvt_k<<<dim3(12, 256), 256, 0, stream>>>(tb, A);                       // t -> A (NHWC)
    mgemm_k<<<dim3(128, 3), 256, 0, stream>>>(WQT, A, A, Bb, 384, 0);       // qT -> B
    dw_nhwc_k<<<2048, 384, 0, stream>>>(Bb, A, DWT_QT);                     // qtd -> A
    tcvt_k<<<dim3(12, 256), 256, 0, stream>>>(xb, Bb);                      // x -> B
    mgemm_k<<<dim3(128, 3), 256, 0, stream>>>(WK, Bb, Bb, Cb, 384, 2);      // k (NCHW) -> C
    dw_nchw_k<<<dim3(64, 384), 256, 0, stream>>>(Cb, Db, w_k_dw);           // kd -> D
    mgemm_k<<<dim3(128, 3), 256, 0, stream>>>(WQ, Bb, Bb, Cb, 384, 0);      // q -> C
    dw_nhwc_k<<<2048, 384, 0, stream>>>(Cb, O, DWT_Q);                      // qd -> O
    mgemm_k<<<dim3(128, 3), 256, 0, stream>>>(WV, Bb, Bb, Cb, 384, 0);      // v -> C
    dw_nhwc_k<<<2048, 384, 0, stream>>>(Cb, Bb, DWT_V);                     // vd -> B
    mgemm_k<<<dim3(128, 3), 256, 0, stream>>>(WQCAT, O, A, Cb, 768, 2);     // qf (NCHW) -> C
    row_sumsq_k<<<dim3(384, 1, 2), 256, 0, stream>>>(Cb, Db, nqb, nkb);
    gramn_k<<<dim3(9, 8, 8), 256, 0, stream>>>(Cb, Db, Gb);
    attn_softmax_k<<<8, 64, 0, stream>>>(Gb, nqb, nkb, temp, attnb);
    avn_k<<<dim3(64, 8), 256, 0, stream>>>(attnb, Bb, outb);
  }
}

// Round 3
// 1126.903 us; speedup vs baseline: 4.6576x; 1.3049x over previous
//
#include <hip/hip_runtime.h>

// PA_MSA: MFMA bf16 GEMM + parallel tap-major depthwise conv + MFMA Gram.
// B=4, C=384, H=W=128, heads=8, ch=48.

typedef unsigned short u16;
typedef __attribute__((ext_vector_type(8))) short s16x8;
typedef __attribute__((ext_vector_type(4))) short s16x4;
typedef __attribute__((ext_vector_type(4))) float f32x4;
typedef __attribute__((ext_vector_type(8))) __bf16 bf16x8;

#define P_HW 16384
#define C_DIM 384

__device__ __forceinline__ u16 f2b(float f) {
  union { float f; unsigned u; } v; v.f = f;
  unsigned u = v.u;
  return (u16)((u + 0x7FFFu + ((u >> 16) & 1u)) >> 16);  // RNE
}
__device__ __forceinline__ float b2f(u16 h) {
  union { unsigned u; float f; } v; v.u = ((unsigned)h) << 16; return v.f;
}

// ---------- utility ----------
__global__ void zerof_k(float* __restrict__ p, int n) {
  int i = blockIdx.x * 256 + threadIdx.x;
  if (i < n) p[i] = 0.f;
}

// fp32 NCHW (384,16384) -> bf16 NHWC (16384,384), one batch
__global__ __launch_bounds__(256) void tcvt_k(const float* __restrict__ in, u16* __restrict__ out) {
  const int tid = threadIdx.x;
  const int c0 = blockIdx.x * 32 + (tid & 3) * 8;
  const int p  = blockIdx.y * 64 + (tid >> 2);
  u16 tmp[8];
#pragma unroll
  for (int u = 0; u < 8; u++) tmp[u] = f2b(in[(size_t)(c0 + u) * P_HW + p]);
  *(s16x8*)(out + (size_t)p * C_DIM + c0) = *(s16x8*)tmp;
}

// convert the 5 weight matrices fp32 -> bf16, concatenated into dst.
__global__ __launch_bounds__(256) void cvtw_k(const float* __restrict__ w_q, const float* __restrict__ w_qT,
                                              const float* __restrict__ w_qcat, const float* __restrict__ w_k,
                                              const float* __restrict__ w_v, u16* __restrict__ dst) {
  int i = blockIdx.x * 256 + threadIdx.x;
  if (i >= 884736) return;
  float v;
  if (i < 147456) v = w_q[i];
  else if (i < 294912) v = w_qT[i - 147456];
  else if (i < 589824) v = w_qcat[i - 294912];
  else if (i < 737280) v = w_k[i - 589824];
  else v = w_v[i - 737280];
  dst[i] = f2b(v);
}

// transpose dw weights (C,1,3,3) -> [tap][c] float, 3 matrices (q, qT, v)
__global__ __launch_bounds__(384) void cvtdw_k(const float* __restrict__ w_q_dw,
                                               const float* __restrict__ w_qT_dw,
                                               const float* __restrict__ w_v_dw,
                                               float* __restrict__ dst) {
  const int c = threadIdx.x;
  const float* src = (blockIdx.x == 0) ? w_q_dw : (blockIdx.x == 1) ? w_qT_dw : w_v_dw;
  float* d = dst + blockIdx.x * 3456;
#pragma unroll
  for (int t = 0; t < 9; t++) d[t * C_DIM + c] = src[c * 9 + t];
}

// ---------- MFMA GEMM: out[o][p] = sum_c W[o][c] * Act[p][c] ----------
// Grid (128, 3), block 256 (4 waves, each 64x64 of the 128x128 tile).
__global__ __launch_bounds__(256) void mgemm_k(const u16* __restrict__ Wb,
    const u16* __restrict__ B1, const u16* __restrict__ B2,
    u16* __restrict__ outp, int K, int mode) {
  __shared__ __align__(16) u16 lA[128 * 64];  // weights tile [o_local][k], 16KB
  __shared__ __align__(16) u16 lB[128 * 64];  // act tile [p_local][k], 16KB
  const int tid = threadIdx.x;
  const int lane = tid & 63;
  const int wv = tid >> 6;
  const int wo = (wv >> 1) * 64;   // wave o-offset in tile
  const int wp = (wv & 1) * 64;    // wave p-offset in tile
  const int o0 = blockIdx.y * 128;
  const int p0 = blockIdx.x * 128;
  const int fr = lane & 15;        // A row (o) / B row (p) within 16x16 frag
  const int fg = lane >> 4;        // k-group (8 contiguous k each)
  const int sr = tid >> 3;         // staging row base (0..31)
  const int sc = tid & 7;          // staging 16B-chunk (0..7)

  f32x4 acc[4][4] = {};            // [mo][np]

  for (int kc = 0; kc < K; kc += 64) {
    const u16* Bsrc = (kc < 384) ? B1 : B2;
    const int kk = (kc < 384) ? kc : kc - 384;
    __syncthreads();
#pragma unroll
    for (int s = 0; s < 4; s++) {
      const int r = sr + s * 32;
      const int slot = (sc ^ (r & 7)) * 8;   // XOR swizzle, 16B granularity
      *(s16x8*)&lA[r * 64 + slot] = *(const s16x8*)(Wb + (size_t)(o0 + r) * K + kc + sc * 8);
      *(s16x8*)&lB[r * 64 + slot] = *(const s16x8*)(Bsrc + (size_t)(p0 + r) * C_DIM + kk + sc * 8);
    }
    __syncthreads();
#pragma unroll
    for (int ks = 0; ks < 2; ks++) {   // two k=32 sub-steps of BK=64
      bf16x8 af[4], bfv[4];
#pragma unroll
      for (int i = 0; i < 4; i++) {
        const int ra = wo + i * 16 + fr;
        af[i]  = *(const bf16x8*)&lA[ra * 64 + (((ks * 4 + fg) ^ (ra & 7)) * 8)];
        const int rb = wp + i * 16 + fr;
        bfv[i] = *(const bf16x8*)&lB[rb * 64 + (((ks * 4 + fg) ^ (rb & 7)) * 8)];
      }
#pragma unroll
      for (int mo = 0; mo < 4; mo++)
#pragma unroll
        for (int np = 0; np < 4; np++)
          acc[mo][np] = __builtin_amdgcn_mfma_f32_16x16x32_bf16(af[mo], bfv[np], acc[mo][np], 0, 0, 0);
    }
  }

  // D layout: row(o) = fg*4 + reg, col(p) = fr  (within each 16x16 frag)
  const int dg = fg * 4;
  if (mode == 0) {
#pragma unroll
    for (int np = 0; np < 4; np++) {
      const int p = p0 + wp + np * 16 + fr;
      u16* dst = outp + (size_t)p * C_DIM + o0 + wo + dg;
#pragma unroll
      for (int mo = 0; mo < 4; mo++) {
        u16 t4[4];
#pragma unroll
        for (int r = 0; r < 4; r++) t4[r] = f2b(acc[mo][np][r]);
        *(s16x4*)(dst + mo * 16) = *(const s16x4*)t4;
      }
    }
  } else {
#pragma unroll
    for (int mo = 0; mo < 4; mo++)
#pragma unroll
      for (int r = 0; r < 4; r++) {
        const int o = o0 + wo + mo * 16 + dg + r;
        u16* dst = outp + (size_t)o * P_HW + p0 + wp + fr;
#pragma unroll
        for (int np = 0; np < 4; np++) dst[np * 16] = f2b(acc[mo][np][r]);
      }
  }
}

// ---------- depthwise 3x3, NHWC bf16 -> NHWC bf16, tap-major parallel ----------
// wT layout [9][384] float. Grid 2048, block 384: thread = (pixel_local 0..7, cgroup 0..47).
__global__ __launch_bounds__(384) void dw_nhwc_k(const u16* __restrict__ in, u16* __restrict__ out,
                                                 const float* __restrict__ wT) {
  const int tid = threadIdx.x;
  const int cg = tid % 48;
  const int pl = tid / 48;
  const int p = blockIdx.x * 8 + pl;
  const int y = p >> 7, x = p & 127;
  const int c0 = cg * 8;
  float acc[8] = {};
#pragma unroll
  for (int ky = 0; ky < 3; ky++) {
    const int yy = y + ky - 1;
    if (yy < 0 || yy > 127) continue;
#pragma unroll
    for (int kx = 0; kx < 3; kx++) {
      const int xx = x + kx - 1;
      if (xx < 0 || xx > 127) continue;
      s16x8 v8 = *(const s16x8*)(in + (size_t)(yy * 128 + xx) * C_DIM + c0);
      const float* wr = wT + (ky * 3 + kx) * C_DIM + c0;
      f32x4 w0 = *(const f32x4*)wr;
      f32x4 w1 = *(const f32x4*)(wr + 4);
#pragma unroll
      for (int u = 0; u < 4; u++) acc[u] += b2f((u16)v8[u]) * w0[u];
#pragma unroll
      for (int u = 0; u < 4; u++) acc[4 + u] += b2f((u16)v8[4 + u]) * w1[u];
    }
  }
  u16 tmp[8];
#pragma unroll
  for (int u = 0; u < 8; u++) tmp[u] = f2b(acc[u]);
  *(s16x8*)(out + (size_t)p * C_DIM + c0) = *(s16x8*)tmp;
}

// ---------- depthwise 3x3, NCHW bf16 -> NCHW bf16 (one batch) ----------
__global__ __launch_bounds__(256) void dw_nchw_k(const u16* __restrict__ in, u16* __restrict__ out,
                                                 const float* __restrict__ w) {
  const int tid = threadIdx.x;
  const int x = tid & 127;
  const int y = blockIdx.x * 2 + (tid >> 7);
  const int c = blockIdx.y;
  float wr[9];
#pragma unroll
  for (int t = 0; t < 9; t++) wr[t] = w[c * 9 + t];
  const u16* base = in + (size_t)c * P_HW;
  float acc = 0.f;
#pragma unroll
  for (int ky = 0; ky < 3; ky++) {
    int yy = y + ky - 1;
    if (yy < 0 || yy > 127) continue;
#pragma unroll
    for (int kx = 0; kx < 3; kx++) {
      int xx = x + kx - 1;
      if (xx < 0 || xx > 127) continue;
      acc += b2f(base[yy * 128 + xx]) * wr[ky * 3 + kx];
    }
  }
  out[(size_t)c * P_HW + y * 128 + x] = f2b(acc);
}

// ---------- per-row sum of squares (one batch; z: 0=q,1=k) ----------
__global__ __launch_bounds__(256) void row_sumsq_k(const u16* __restrict__ q, const u16* __restrict__ k,
                                                   float* __restrict__ nq, float* __restrict__ nk) {
  const int c = blockIdx.x, t = blockIdx.z;
  const u16* src = (t == 0) ? q : k;
  float* dst = (t == 0) ? nq : nk;
  const u16* row = src + (size_t)c * P_HW;
  float s = 0.f;
  for (int i = threadIdx.x * 8; i < P_HW; i += 2048) {
    s16x8 v = *(const s16x8*)(row + i);
#pragma unroll
    for (int j = 0; j < 8; j++) { float f = b2f((u16)v[j]); s += f * f; }
  }
  __shared__ float red[256];
  red[threadIdx.x] = s;
  __syncthreads();
  for (int off = 128; off > 0; off >>= 1) {
    if (threadIdx.x < off) red[threadIdx.x] += red[threadIdx.x + off];
    __syncthreads();
  }
  if (threadIdx.x == 0) dst[c] = red[0];
}

// ---------- MFMA Gram (one batch): G[h][i][j] += sum_p q[h*48+i][p] k[h*48+j][p] ----------
// q,k NCHW bf16 [384][16384]. Grid (32, 8): bx = p-chunk (512), by = head. Block 256 (4 waves).
// Each wave: 128 p = 4 k-steps x {6 direct 16B loads + 9 MFMA}. LDS reduce, then global atomics.
__global__ __launch_bounds__(256) void gram_k(const u16* __restrict__ q, const u16* __restrict__ k,
                                              float* __restrict__ G) {
  __shared__ float lG[2304];
  const int tid = threadIdx.x;
  const int lane = tid & 63;
  const int wv = tid >> 6;
  const int h = blockIdx.y;
  const int fr = lane & 15;        // fragment row
  const int fg = lane >> 4;        // k-group (8 contiguous p)
  const int pbase = blockIdx.x * 512 + wv * 128;

  const u16* qh = q + (size_t)h * 48 * P_HW;
  const u16* kh = k + (size_t)h * 48 * P_HW;

  f32x4 acc[3][3] = {};
#pragma unroll
  for (int ps = 0; ps < 128; ps += 32) {
    const int p = pbase + ps + fg * 8;
    bf16x8 af[3], bf_[3];
#pragma unroll
    for (int t = 0; t < 3; t++) {
      af[t]  = *(const bf16x8*)(qh + (size_t)(t * 16 + fr) * P_HW + p);
      bf_[t] = *(const bf16x8*)(kh + (size_t)(t * 16 + fr) * P_HW + p);
    }
#pragma unroll
    for (int ti = 0; ti < 3; ti++)
#pragma unroll
      for (int tj = 0; tj < 3; tj++)
        acc[ti][tj] = __builtin_amdgcn_mfma_f32_16x16x32_bf16(af[ti], bf_[tj], acc[ti][tj], 0, 0, 0);
  }

  for (int e = tid; e < 2304; e += 256) lG[e] = 0.f;
  __syncthreads();
  // D layout: row(i) = fg*4 + r, col(j) = fr  (within each 16x16 frag)
#pragma unroll
  for (int ti = 0; ti < 3; ti++)
#pragma unroll
    for (int tj = 0; tj < 3; tj++)
#pragma unroll
      for (int r = 0; r < 4; r++) {
        const int i = ti * 16 + fg * 4 + r;
        const int j = tj * 16 + fr;
        atomicAdd(&lG[i * 48 + j], acc[ti][tj][r]);
      }
  __syncthreads();
  float* Gh = G + (size_t)h * 2304;
  for (int e = tid; e < 2304; e += 256) atomicAdd(&Gh[e], lG[e]);
}

// ---------- softmax (one batch): fp32 attn out [8][48][48] ----------
__global__ void attn_softmax_k(const float* __restrict__ G, const float* __restrict__ nqA,
                               const float* __restrict__ nkA, const float* __restrict__ temp,
                               float* __restrict__ attnf) {
  const int h = blockIdx.x;
  const int i = threadIdx.x;
  __shared__ float mk[48];
  if (i < 48) mk[i] = fmaxf(sqrtf(nkA[h * 48 + i]), 1e-12f);
  __syncthreads();
  if (i < 48) {
    float mq = fmaxf(sqrtf(nqA[h * 48 + i]), 1e-12f);
    float T = temp[h];
    const float* g = G + ((size_t)h * 48 + i) * 48;
    float L[48];
    float mx = -1e30f;
    for (int j = 0; j < 48; j++) {
      L[j] = T * g[j] / (mq * mk[j]);
      mx = fmaxf(mx, L[j]);
    }
    float sum = 0.f;
    for (int j = 0; j < 48; j++) { L[j] = expf(L[j] - mx); sum += L[j]; }
    float inv = 1.f / sum;
    float* d = attnf + ((size_t)h * 48 + i) * 48;
    for (int j = 0; j < 48; j++) d[j] = L[j] * inv;
  }
}

// ---------- AV (one batch): out[h*48+i][p] = sum_j attn[h][i][j] v[p][h*48+j] ----------
// grid (64, 8): by = head. Per-head LDS attn staging.
__global__ __launch_bounds__(256) void avn_k(const float* __restrict__ attnf, const u16* __restrict__ v,
                                             float* __restrict__ out) {
  __shared__ float la[2304];
  const int tid = threadIdx.x;
  const int h = blockIdx.y;
  const int p = blockIdx.x * 256 + tid;
  for (int idx = tid; idx < 2304; idx += 256) la[idx] = attnf[h * 2304 + idx];
  __syncthreads();
  const u16* vp = v + (size_t)p * C_DIM + h * 48;
  float vf[48];
#pragma unroll
  for (int s = 0; s < 6; s++) {
    s16x8 t8 = *(const s16x8*)(vp + s * 8);
#pragma unroll
    for (int u = 0; u < 8; u++) vf[s * 8 + u] = b2f((u16)t8[u]);
  }
  for (int i = 0; i < 48; i++) {
    const float* row = &la[i * 48];
    float acc = 0.f;
#pragma unroll
    for (int j = 0; j < 48; j += 4) {
      acc += row[j] * vf[j] + row[j + 1] * vf[j + 1] + row[j + 2] * vf[j + 2] + row[j + 3] * vf[j + 3];
    }
    out[(size_t)(h * 48 + i) * P_HW + p] = acc;
  }
}

// ---------- launch ----------
extern "C" void kernel_launch(void* const* d_in, const int* in_sizes, int n_in,
                              void* d_out, int out_size, void* d_ws, size_t ws_size,
                              hipStream_t stream) {
  const float* x      = (const float*)d_in[0];
  const float* t      = (const float*)d_in[1];
  const float* w_q    = (const float*)d_in[2];
  const float* w_q_dw = (const float*)d_in[3];
  const float* w_qT   = (const float*)d_in[4];
  const float* w_qT_dw= (const float*)d_in[5];
  const float* w_qcat = (const float*)d_in[6];
  const float* w_k    = (const float*)d_in[7];
  const float* w_k_dw = (const float*)d_in[8];
  const float* w_v    = (const float*)d_in[9];
  const float* w_v_dw = (const float*)d_in[10];
  const float* temp   = (const float*)d_in[11];
  float* out = (float*)d_out;

  // ws: G[32*2304] nq[1536] nk[1536] attnf[32*2304] then 4 bf16 buffers (12.58MB each)
  float* G     = (float*)d_ws;
  float* nq    = G + 73728;
  float* nk    = nq + 1536;
  float* attnf = nk + 1536;
  u16* bufs = (u16*)(attnf + 73728);        // byte offset 602112, 16B-aligned
  const size_t BUFE = (size_t)P_HW * C_DIM; // 6,291,456 elems
  u16* A = bufs;
  u16* Bb = A + BUFE;
  u16* Cb = Bb + BUFE;
  u16* Db = Cb + BUFE;

  // bf16 weights + transposed dw weights live in the second half of batch-3's
  // output quarter: untouched until batch-3's final avn_k (runs after all uses).
  u16* Wscr = (u16*)(out + (size_t)3 * C_DIM * P_HW) + BUFE;
  u16* WQ    = Wscr;
  u16* WQT   = Wscr + 147456;
  u16* WQCAT = Wscr + 294912;
  u16* WK    = Wscr + 589824;
  u16* WV    = Wscr + 737280;
  float* DWT   = (float*)(Wscr + 884736);   // 3 x [9][384] float
  float* DWT_Q  = DWT;
  float* DWT_QT = DWT + 3456;
  float* DWT_V  = DWT + 6912;

  zerof_k<<<288, 256, 0, stream>>>(G, 73728);
  cvtw_k<<<3456, 256, 0, stream>>>(w_q, w_qT, w_qcat, w_k, w_v, Wscr);
  cvtdw_k<<<3, 384, 0, stream>>>(w_q_dw, w_qT_dw, w_v_dw, DWT);

  for (int b = 0; b < 4; b++) {
    const float* xb = x + (size_t)b * C_DIM * P_HW;
    const float* tb = t + (size_t)b * C_DIM * P_HW;
    float* outb = out + (size_t)b * C_DIM * P_HW;
    u16* O = (u16*)outb;                    // batch-local scratch inside own out region
    float* Gb = G + (size_t)b * 8 * 2304;
    float* nqb = nq + (size_t)b * C_DIM;
    float* nkb = nk + (size_t)b * C_DIM;
    float* attnb = attnf + (size_t)b * 8 * 2304;

    tcvt_k<<<dim3(12, 256), 256, 0, stream>>>(tb, A);                       // t -> A (NHWC)
    mgemm_k<<<dim3(128, 3), 256, 0, stream>>>(WQT, A, A, Bb, 384, 0);       // qT -> B
    dw_nhwc_k<<<2048, 384, 0, stream>>>(Bb, A, DWT_QT);                     // qtd -> A
    tcvt_k<<<dim3(12, 256), 256, 0, stream>>>(xb, Bb);                      // x -> B
    mgemm_k<<<dim3(128, 3), 256, 0, stream>>>(WK, Bb, Bb, Cb, 384, 2);      // k (NCHW) -> C
    dw_nchw_k<<<dim3(64, 384), 256, 0, stream>>>(Cb, Db, w_k_dw);           // kd -> D
    mgemm_k<<<dim3(128, 3), 256, 0, stream>>>(WQ, Bb, Bb, Cb, 384, 0);      // q -> C
    dw_nhwc_k<<<2048, 384, 0, stream>>>(Cb, O, DWT_Q);                      // qd -> O
    mgemm_k<<<dim3(128, 3), 256, 0, stream>>>(WV, Bb, Bb, Cb, 384, 0);      // v -> C
    dw_nhwc_k<<<2048, 384, 0, stream>>>(Cb, Bb, DWT_V);                     // vd -> B
    mgemm_k<<<dim3(128, 3), 256, 0, stream>>>(WQCAT, O, A, Cb, 768, 2);     // qf (NCHW) -> C
    row_sumsq_k<<<dim3(384, 1, 2), 256, 0, stream>>>(Cb, Db, nqb, nkb);
    gram_k<<<dim3(32, 8), 256, 0, stream>>>(Cb, Db, Gb);
    attn_softmax_k<<<8, 64, 0, stream>>>(Gb, nqb, nkb, temp, attnb);
    avn_k<<<dim3(64, 8), 256, 0, stream>>>(attnb, Bb, outb);
  }
}